// Round 4
// baseline (1540.469 us; speedup 1.0000x reference)
//
#include <hip/hip_runtime.h>

// MultiHeadAttention pipeline, dtype-adaptive (probe detects fp32 vs bf16 inputs).
// B=4 T=2048 C=2048 H=16 Dh=128.
// All compute in bf16 MFMA on converted workspace copies; per-batch to bound ws.
// ws layout (bhalf elems): 6 slots x 4,194,304 (wt, xcb, qb, kb, vtb, yb)
//   + bc (8192: b_attn||b_proj) + int flag  ~= 50.4 MB.

using bhalf  = __bf16;
using bhalf8 = __attribute__((ext_vector_type(8))) __bf16;   // MFMA A/B frag (4 VGPRs)
using floatx4 = __attribute__((ext_vector_type(4))) float;   // MFMA C/D frag

#define MFMA16(A, B, C) __builtin_amdgcn_mfma_f32_16x16x32_bf16(A, B, C, 0, 0, 0)

__device__ __forceinline__ void gload16(const void* g, void* l) {
  __builtin_amdgcn_global_load_lds(
      (const __attribute__((address_space(1))) unsigned int*)g,
      (__attribute__((address_space(3))) unsigned int*)l, 16, 0, 0);
}

__device__ __forceinline__ float fin(float v) {
  return (__builtin_fabsf(v) < 1e30f) ? v : 0.0f;  // non-finite/garbage -> 0
}

constexpr int Bn = 4, Tn = 2048, Cn = 2048, Hn = 16, Dh = 128;
constexpr int Kdim = Cn;

// ---------------- dtype probe: low 16 bits of each 32b word as bf16 exponent.
// bf16 array: low half = element 2i ~ N(0,1) -> exp field in [100,140] ~always.
// fp32 array: low half = mantissa bits -> exp field ~uniform (hit rate ~16%).
__global__ __launch_bounds__(256) void probe_k(const unsigned int* __restrict__ xw,
                                               int* __restrict__ flag) {
  __shared__ int cnt;
  if (threadIdx.x == 0) cnt = 0;
  __syncthreads();
  int lc = 0;
  for (int i = threadIdx.x; i < 4096; i += 256) {
    const unsigned e = (xw[i] >> 7) & 0xFFu;
    lc += (e >= 100u && e <= 140u) ? 1 : 0;
  }
  atomicAdd(&cnt, lc);
  __syncthreads();
  if (threadIdx.x == 0) *flag = (cnt < 2048) ? 1 : 0;  // 1 = fp32 inputs
}

// ---------------- convert raw (fp32 or bf16 per flag) -> bf16
__global__ __launch_bounds__(256) void cvt_k(const void* __restrict__ in, size_t eoff,
                                             bhalf* __restrict__ out, int n,
                                             const int* __restrict__ flag) {
  const bool f32 = (*flag != 0);
  const int i = (blockIdx.x * 256 + threadIdx.x) * 4;
  if (i + 3 < n) {
    if (f32) {
      const float4 u = *reinterpret_cast<const float4*>((const float*)in + eoff + i);
      out[i + 0] = (bhalf)u.x; out[i + 1] = (bhalf)u.y;
      out[i + 2] = (bhalf)u.z; out[i + 3] = (bhalf)u.w;
    } else {
      *reinterpret_cast<ushort4*>(out + i) =
          *reinterpret_cast<const ushort4*>((const unsigned short*)in + eoff + i);
    }
  } else {
    for (int j = i; j < n; j++)
      out[j] = f32 ? (bhalf)((const float*)in)[eoff + j]
                   : (bhalf)__builtin_bit_cast(bhalf, ((const unsigned short*)in)[eoff + j]);
  }
}

// ---------------- transpose + convert: out[c][r] = cvt(in[r*ldin + coff + c])
__global__ __launch_bounds__(256) void transpose_cvt(const void* __restrict__ in,
                                                     bhalf* __restrict__ out,
                                                     int ldin, int ldout, int coff,
                                                     const int* __restrict__ flag) {
  __shared__ unsigned short tile[64][65];
  const bool f32 = (*flag != 0);
  const int c0 = blockIdx.x * 64, r0 = blockIdx.y * 64;
  const int tx = threadIdx.x & 15, ty = threadIdx.x >> 4;
#pragma unroll
  for (int i = 0; i < 4; i++) {
    const int r = ty + i * 16;
    const size_t src = (size_t)(r0 + r) * ldin + coff + c0 + tx * 4;
    if (f32) {
      const float4 u = *reinterpret_cast<const float4*>((const float*)in + src);
      tile[r][tx * 4 + 0] = __builtin_bit_cast(unsigned short, (bhalf)u.x);
      tile[r][tx * 4 + 1] = __builtin_bit_cast(unsigned short, (bhalf)u.y);
      tile[r][tx * 4 + 2] = __builtin_bit_cast(unsigned short, (bhalf)u.z);
      tile[r][tx * 4 + 3] = __builtin_bit_cast(unsigned short, (bhalf)u.w);
    } else {
      const ushort4 u = *reinterpret_cast<const ushort4*>((const unsigned short*)in + src);
      tile[r][tx * 4 + 0] = u.x; tile[r][tx * 4 + 1] = u.y;
      tile[r][tx * 4 + 2] = u.z; tile[r][tx * 4 + 3] = u.w;
    }
  }
  __syncthreads();
#pragma unroll
  for (int i = 0; i < 4; i++) {
    const int c = ty + i * 16;
    ushort4 u;
    u.x = tile[tx * 4 + 0][c]; u.y = tile[tx * 4 + 1][c];
    u.z = tile[tx * 4 + 2][c]; u.w = tile[tx * 4 + 3][c];
    *reinterpret_cast<ushort4*>((unsigned short*)out + (size_t)(c0 + c) * ldout + r0 + tx * 4) = u;
  }
}

// ---------------- 128x128x(BK=64) GEMM, A[2048][2048] bf16, Bt[2048][2048] bf16.
// MODE 0: out [H,T,Dh] scatter (+bias)      (q_b, k_b)
// MODE 1: out (fp32|bf16 per flag) row-major [T][Cn] at elem offset obase (+bias)
// MODE 2: swapped operands, out [H,Dh,T] (+bias over d)  (vt_b)
template <int MODE>
__global__ __launch_bounds__(256, 3) void gemm128(const bhalf* __restrict__ A,
                                                  const bhalf* __restrict__ Bt,
                                                  const bhalf* __restrict__ bias,
                                                  void* __restrict__ ovoid,
                                                  size_t obase,
                                                  const int* __restrict__ flag) {
  __shared__ __align__(16) bhalf sA[128 * 64];
  __shared__ __align__(16) bhalf sB[128 * 64];
  const int tid = threadIdx.x;
  const int lane = tid & 63, wv = tid >> 6;
  const int ln = lane & 15, quad = lane >> 4;
  const int wr = wv >> 1, wc = wv & 1;  // 2x2 wave grid, 64x64 per wave
  const int m0 = blockIdx.y * 128, n0 = blockIdx.x * 128;

  const floatx4 fzero = {0.f, 0.f, 0.f, 0.f};
  floatx4 acc[4][4];
#pragma unroll
  for (int i = 0; i < 4; i++)
#pragma unroll
    for (int j = 0; j < 4; j++) acc[i][j] = fzero;

  const bhalf* aStage = A + (size_t)(m0 + wv * 32 + (lane >> 3)) * Kdim + (lane & 7) * 8;
  const bhalf* bStage = Bt + (size_t)(n0 + wv * 32 + (lane >> 3)) * Kdim + (lane & 7) * 8;
  bhalf* sAw = &sA[(wv * 32) * 64];
  bhalf* sBw = &sB[(wv * 32) * 64];

  for (int k0 = 0; k0 < Kdim; k0 += 64) {
#pragma unroll
    for (int j = 0; j < 4; j++) gload16(aStage + (size_t)j * 8 * Kdim + k0, sAw + j * 8 * 64);
#pragma unroll
    for (int j = 0; j < 4; j++) gload16(bStage + (size_t)j * 8 * Kdim + k0, sBw + j * 8 * 64);
    __syncthreads();
#pragma unroll
    for (int ks = 0; ks < 2; ks++) {
      bhalf8 af[4], bfr[4];
#pragma unroll
      for (int mi = 0; mi < 4; mi++)
        af[mi] = *reinterpret_cast<const bhalf8*>(&sA[(wr * 64 + mi * 16 + ln) * 64 + ks * 32 + quad * 8]);
#pragma unroll
      for (int ni = 0; ni < 4; ni++)
        bfr[ni] = *reinterpret_cast<const bhalf8*>(&sB[(wc * 64 + ni * 16 + ln) * 64 + ks * 32 + quad * 8]);
#pragma unroll
      for (int i = 0; i < 4; i++)
#pragma unroll
        for (int j = 0; j < 4; j++) {
          if (MODE == 2)
            acc[i][j] = MFMA16(bfr[i], af[j], acc[i][j]);  // D^T: acc[ni][mi]
          else
            acc[i][j] = MFMA16(af[i], bfr[j], acc[i][j]);  // D:   acc[mi][ni]
        }
    }
    __syncthreads();
  }

  if (MODE == 0) {
    bhalf* o0 = (bhalf*)ovoid;
    float bv[4];
#pragma unroll
    for (int ni = 0; ni < 4; ni++) bv[ni] = (float)bias[n0 + wc * 64 + ni * 16 + ln];
    const int h = n0 >> 7;
    const size_t base = ((size_t)h * Tn + m0) * Dh;
#pragma unroll
    for (int mi = 0; mi < 4; mi++)
#pragma unroll
      for (int ni = 0; ni < 4; ni++)
#pragma unroll
        for (int r = 0; r < 4; r++) {
          const int t = wr * 64 + mi * 16 + quad * 4 + r;  // C/D: row=quad*4+reg
          const int d = wc * 64 + ni * 16 + ln;            // C/D: col=lane&15
          o0[base + (size_t)t * Dh + d] = (bhalf)fin(acc[mi][ni][r] + bv[ni]);
        }
  } else if (MODE == 1) {
    const bool f32 = (*flag != 0);
    float bv[4];
#pragma unroll
    for (int ni = 0; ni < 4; ni++) bv[ni] = (float)bias[n0 + wc * 64 + ni * 16 + ln];
#pragma unroll
    for (int mi = 0; mi < 4; mi++)
#pragma unroll
      for (int ni = 0; ni < 4; ni++)
#pragma unroll
        for (int r = 0; r < 4; r++) {
          const int row = m0 + wr * 64 + mi * 16 + quad * 4 + r;
          const int col = n0 + wc * 64 + ni * 16 + ln;
          float val = acc[mi][ni][r] + bv[ni];
          if (!(__builtin_fabsf(val) < 1e30f)) val = f32 ? 777.0f : 555.0f;  // diag code
          const size_t idx = obase + (size_t)row * Cn + col;
          if (f32) ((float*)ovoid)[idx] = val;
          else     ((bhalf*)ovoid)[idx] = (bhalf)val;
        }
  } else {  // MODE 2: acc[ni][mi]; D^T row = d, col = t
    bhalf* o0 = (bhalf*)ovoid;
    const int h = n0 >> 7;
    const size_t base = (size_t)h * Dh * Tn;
#pragma unroll
    for (int ni = 0; ni < 4; ni++)
#pragma unroll
      for (int mi = 0; mi < 4; mi++)
#pragma unroll
        for (int r = 0; r < 4; r++) {
          const int d = wc * 64 + ni * 16 + quad * 4 + r;
          const int t = m0 + wr * 64 + mi * 16 + ln;
          const float bb = (float)bias[n0 + d];
          o0[base + (size_t)d * Tn + t] = (bhalf)fin(acc[ni][mi][r] + bb);
        }
  }
}

// ---------------- flash attention, one batch: block = (q-tile, head)
// q,k: [H,T,Dh]; vt: [H,Dh,T]; out y: [T,C]
__global__ __launch_bounds__(256, 2) void flash_attn_k(const bhalf* __restrict__ Qb,
                                                       const bhalf* __restrict__ Kb,
                                                       const bhalf* __restrict__ VTb,
                                                       bhalf* __restrict__ Ob) {
  __shared__ __align__(16) bhalf sK[128 * 128];   // K tile [kpos][d]; reused as P
  __shared__ __align__(16) bhalf sVT[128 * 128];  // V^T tile [d][kpos]
  const int tid = threadIdx.x;
  const int lane = tid & 63, wv = tid >> 6;
  const int ln = lane & 15, quad = lane >> 4;
  const int h = blockIdx.y;
  const int t0q = blockIdx.x * 128;
  const size_t hb = (size_t)h * Tn * Dh;
  constexpr float kSc = 0.08838834764831845f * 1.4426950408889634f;  // 1/sqrt(Dh)*log2e

  bhalf8 qf[2][4];
#pragma unroll
  for (int mi = 0; mi < 2; mi++)
#pragma unroll
    for (int kd = 0; kd < 4; kd++)
      qf[mi][kd] = *reinterpret_cast<const bhalf8*>(
          Qb + hb + (size_t)(t0q + wv * 32 + mi * 16 + ln) * Dh + kd * 32 + quad * 8);

  const floatx4 fzero = {0.f, 0.f, 0.f, 0.f};
  floatx4 oAcc[2][8];
#pragma unroll
  for (int mi = 0; mi < 2; mi++)
#pragma unroll
    for (int di = 0; di < 8; di++) oAcc[mi][di] = fzero;
  float mrow[8], lrow[8];
#pragma unroll
  for (int i = 0; i < 8; i++) { mrow[i] = -1e30f; lrow[i] = 0.f; }

  const bhalf* kStage = Kb + hb + (size_t)(wv * 32 + (lane >> 4)) * Dh + (lane & 15) * 8;
  const bhalf* vStage = VTb + hb + (size_t)(wv * 32 + (lane >> 4)) * Tn + (lane & 15) * 8;
  bhalf* sKw = &sK[(wv * 32) * 128];
  bhalf* sVw = &sVT[(wv * 32) * 128];

  for (int t0k = 0; t0k < Tn; t0k += 128) {
#pragma unroll
    for (int j = 0; j < 8; j++) gload16(kStage + (size_t)(t0k + j * 4) * Dh, sKw + j * 4 * 128);
#pragma unroll
    for (int j = 0; j < 8; j++) gload16(vStage + t0k + (size_t)j * 4 * Tn, sVw + j * 4 * 128);
    __syncthreads();

    floatx4 sAcc[2][8];
#pragma unroll
    for (int mi = 0; mi < 2; mi++)
#pragma unroll
      for (int ni = 0; ni < 8; ni++) sAcc[mi][ni] = fzero;
#pragma unroll
    for (int kd = 0; kd < 4; kd++) {
#pragma unroll
      for (int ni = 0; ni < 8; ni++) {
        const bhalf8 bfr = *reinterpret_cast<const bhalf8*>(&sK[(ni * 16 + ln) * 128 + kd * 32 + quad * 8]);
#pragma unroll
        for (int mi = 0; mi < 2; mi++) sAcc[mi][ni] = MFMA16(qf[mi][kd], bfr, sAcc[mi][ni]);
      }
    }

#pragma unroll
    for (int mi = 0; mi < 2; mi++)
#pragma unroll
      for (int ni = 0; ni < 8; ni++)
#pragma unroll
        for (int r = 0; r < 4; r++) {
          const float s = sAcc[mi][ni][r];
          sAcc[mi][ni][r] = (__builtin_fabsf(s) < 1e30f) ? s : -3.0e38f;
        }

#pragma unroll
    for (int mi = 0; mi < 2; mi++)
#pragma unroll
      for (int r = 0; r < 4; r++) {
        const int ix = mi * 4 + r;
        float zm = sAcc[mi][0][r];
#pragma unroll
        for (int ni = 1; ni < 8; ni++) zm = fmaxf(zm, sAcc[mi][ni][r]);
        zm *= kSc;
        zm = fmaxf(zm, __shfl_xor(zm, 1));
        zm = fmaxf(zm, __shfl_xor(zm, 2));
        zm = fmaxf(zm, __shfl_xor(zm, 4));
        zm = fmaxf(zm, __shfl_xor(zm, 8));
        const float mn = fmaxf(mrow[ix], zm);
        const float al = exp2f(mrow[ix] - mn);
        float rs = 0.f;
#pragma unroll
        for (int ni = 0; ni < 8; ni++) {
          const float p = exp2f(fmaf(sAcc[mi][ni][r], kSc, -mn));
          sAcc[mi][ni][r] = p;
          rs += p;
        }
        rs += __shfl_xor(rs, 1);
        rs += __shfl_xor(rs, 2);
        rs += __shfl_xor(rs, 4);
        rs += __shfl_xor(rs, 8);
        lrow[ix] = lrow[ix] * al + rs;
        mrow[ix] = mn;
#pragma unroll
        for (int di = 0; di < 8; di++) oAcc[mi][di][r] *= al;
      }
    __syncthreads();

#pragma unroll
    for (int mi = 0; mi < 2; mi++)
#pragma unroll
      for (int ni = 0; ni < 8; ni++)
#pragma unroll
        for (int r = 0; r < 4; r++)
          sK[(wv * 32 + mi * 16 + quad * 4 + r) * 128 + ni * 16 + ln] = (bhalf)sAcc[mi][ni][r];
    __syncthreads();

#pragma unroll
    for (int kt = 0; kt < 4; kt++) {
      bhalf8 ap[2];
#pragma unroll
      for (int mi = 0; mi < 2; mi++)
        ap[mi] = *reinterpret_cast<const bhalf8*>(&sK[(wv * 32 + mi * 16 + ln) * 128 + kt * 32 + quad * 8]);
#pragma unroll
      for (int di = 0; di < 8; di++) {
        const bhalf8 bv = *reinterpret_cast<const bhalf8*>(&sVT[(di * 16 + ln) * 128 + kt * 32 + quad * 8]);
#pragma unroll
        for (int mi = 0; mi < 2; mi++) oAcc[mi][di] = MFMA16(ap[mi], bv, oAcc[mi][di]);
      }
    }
    __syncthreads();
  }

#pragma unroll
  for (int mi = 0; mi < 2; mi++)
#pragma unroll
    for (int r = 0; r < 4; r++) {
      const float inv = 1.0f / lrow[mi * 4 + r];
      const int t = t0q + wv * 32 + mi * 16 + quad * 4 + r;
      const size_t rowb = (size_t)t * Cn + h * Dh;
#pragma unroll
      for (int di = 0; di < 8; di++)
        Ob[rowb + di * 16 + ln] = (bhalf)fin(oAcc[mi][di][r] * inv);
    }
}

extern "C" void kernel_launch(void* const* d_in, const int* in_sizes, int n_in,
                              void* d_out, int out_size, void* d_ws, size_t ws_size,
                              hipStream_t stream) {
  const void* x      = d_in[0];
  const void* W_attn = d_in[1];
  const void* b_attn = d_in[2];
  const void* W_proj = d_in[3];
  const void* b_proj = d_in[4];
  bhalf* ws = (bhalf*)d_ws;

  const size_t SLOT = (size_t)Cn * Kdim;  // 4,194,304 elems
  bhalf* wt   = ws + 0 * SLOT;  // transposed+converted W chunk [2048][2048]
  bhalf* xcb  = ws + 1 * SLOT;  // x batch, bf16 [2048][2048]
  bhalf* qb   = ws + 2 * SLOT;  // [H,T,Dh]
  bhalf* kb   = ws + 3 * SLOT;  // [H,T,Dh]
  bhalf* vtb  = ws + 4 * SLOT;  // [H,Dh,T]
  bhalf* yb   = ws + 5 * SLOT;  // [T,C]
  bhalf* bcA  = ws + 6 * SLOT;           // b_attn bf16 (6144)
  bhalf* bcP  = bcA + 3 * Cn;            // b_proj bf16 (2048)
  int*   flag = (int*)(bcP + Cn);        // dtype flag (4-byte aligned)

  const dim3 gT(32, 32), gG(16, 16), gF(16, Hn);

  probe_k<<<1, 256, 0, stream>>>((const unsigned int*)x, flag);
  cvt_k<<<6, 256, 0, stream>>>(b_attn, 0, bcA, 3 * Cn, flag);
  cvt_k<<<2, 256, 0, stream>>>(b_proj, 0, bcP, Cn, flag);

  for (int b = 0; b < Bn; b++) {
    const size_t xoff = (size_t)b * Tn * Cn;
    cvt_k<<<4096, 256, 0, stream>>>(x, xoff, xcb, Tn * Cn, flag);

    transpose_cvt<<<gT, 256, 0, stream>>>(W_attn, wt, 3 * Cn, Kdim, 0 * Cn, flag);
    gemm128<0><<<gG, 256, 0, stream>>>(xcb, wt, bcA + 0 * Cn, qb, 0, flag);

    transpose_cvt<<<gT, 256, 0, stream>>>(W_attn, wt, 3 * Cn, Kdim, 1 * Cn, flag);
    gemm128<0><<<gG, 256, 0, stream>>>(xcb, wt, bcA + 1 * Cn, kb, 0, flag);

    transpose_cvt<<<gT, 256, 0, stream>>>(W_attn, wt, 3 * Cn, Kdim, 2 * Cn, flag);
    gemm128<2><<<gG, 256, 0, stream>>>(xcb, wt, bcA + 2 * Cn, vtb, 0, flag);

    flash_attn_k<<<gF, 256, 0, stream>>>(qb, kb, vtb, yb);

    transpose_cvt<<<gT, 256, 0, stream>>>(W_proj, wt, Kdim, Kdim, 0, flag);
    gemm128<1><<<gG, 256, 0, stream>>>(yb, wt, bcP, d_out, xoff, flag);
  }
}